// Round 3
// baseline (5339.159 us; speedup 1.0000x reference)
//
#include <hip/hip_runtime.h>

#define HW 16384
typedef unsigned int uint32;
typedef unsigned short ushort;

__device__ __forceinline__ float bf2f(ushort u) {
    union { uint32 i; float f; } x; x.i = ((uint32)u) << 16; return x.f;
}
__device__ __forceinline__ ushort f2bf(float f) {
    union { float f; uint32 i; } x; x.f = f;
    uint32 r = x.i + 0x7fffu + ((x.i >> 16) & 1u);
    return (ushort)(r >> 16);
}

// ---- dtype detector: fp32 data read as bf16 halves has wild exponents ----
__global__ __launch_bounds__(256) void detect_dtype(const ushort* __restrict__ x,
                                                    int* __restrict__ flag) {
    __shared__ int cnt;
    if (threadIdx.x == 0) cnt = 0;
    __syncthreads();
    int c = 0;
    for (int i = threadIdx.x; i < 8192; i += 256) {
        int e = (x[i] >> 7) & 0xFF;   // bf16 exponent field
        if (e >= 200) c++;            // |v| >= ~2^72: impossible for N(0,1) bf16
    }
    atomicAdd(&cnt, c);
    __syncthreads();
    if (threadIdx.x == 0) *flag = (cnt > 100) ? 1 : 0;  // 1 => inputs are fp32
}

// ---- weight convert (either dtype) -> fp32: wqkv transposed, dw, wproj, temp ----
__global__ __launch_bounds__(256) void convert_weights(
    const void* __restrict__ wqkv, const void* __restrict__ dw0,
    const void* __restrict__ dw1, const void* __restrict__ dw2,
    const void* __restrict__ wproj, const void* __restrict__ temp,
    const int* __restrict__ flag,
    float* __restrict__ wqkv_t, float* __restrict__ dwf,
    float* __restrict__ wprojf, float* __restrict__ tempf) {
    int fl = *flag;
    int idx = blockIdx.x * 256 + threadIdx.x;
#define RD(p, k) (fl ? ((const float*)(p))[k] : bf2f(((const ushort*)(p))[k]))
    if (idx < 110592) {  // w_qkv [576][192] -> wt [192][576]
        int o = idx / 192, c = idx % 192;
        wqkv_t[c * 576 + o] = RD(wqkv, idx);
        return;
    }
    idx -= 110592;
    if (idx < 15552) {   // 3 x [576*9]
        const void* p = (idx < 5184) ? dw0 : ((idx < 10368) ? dw1 : dw2);
        dwf[idx] = RD(p, idx % 5184);
        return;
    }
    idx -= 15552;
    if (idx < 110592) {  // w_proj [192][576] kept row-major
        wprojf[idx] = RD(wproj, idx);
        return;
    }
    idx -= 110592;
    if (idx < 8) tempf[idx] = RD(temp, idx);
#undef RD
}

// ---- qkv = w_qkv @ x : per-block 128-n tile, all 576 o, K=192; qkv stored bf16 ----
__global__ __launch_bounds__(256) void qkv_gemm(const void* __restrict__ xv,
    const float* __restrict__ wt, const int* __restrict__ flag,
    ushort* __restrict__ qkv) {
    int fl = *flag;
    int blk = blockIdx.x;
    int b = blk >> 7; int n0 = (blk & 127) << 7;
    int t = threadIdx.x; int n = t & 127; int half = t >> 7;  // wave-uniform
    __shared__ ushort xs[192 * 128];
    size_t base = (size_t)b * 192 * HW + n0;
    if (fl) {
        const float* src = (const float*)xv + base;
        for (int idx = t; idx < 192 * 128; idx += 256) {
            int r = idx >> 7, cu = idx & 127;
            xs[idx] = f2bf(src[(size_t)r * HW + cu]);
        }
    } else {
        const ushort* src = (const ushort*)xv + base;
        for (int idx = t; idx < 192 * 128; idx += 256) {
            int r = idx >> 7, cu = idx & 127;
            xs[idx] = src[(size_t)r * HW + cu];
        }
    }
    __syncthreads();
    for (int oc = 0; oc < 9; ++oc) {
        int o0 = oc * 64 + half * 32;
        float acc[32];
#pragma unroll
        for (int j = 0; j < 32; ++j) acc[j] = 0.f;
        for (int c = 0; c < 192; ++c) {
            float xvv = bf2f(xs[(c << 7) + n]);
            const float* wr = wt + c * 576 + o0;  // wave-uniform row
#pragma unroll
            for (int j = 0; j < 32; ++j) acc[j] = fmaf(wr[j], xvv, acc[j]);
        }
        ushort* dst = qkv + ((size_t)(b * 576 + o0)) * HW + n0 + n;
#pragma unroll
        for (int j = 0; j < 32; ++j) dst[(size_t)j * HW] = f2bf(acc[j]);
    }
}

// ---- fused dwconv(q,k) + gram partials; block = (rowgroup, head, batch) ----
__global__ __launch_bounds__(256) void gram_fused(const ushort* __restrict__ qkv,
    const float* __restrict__ dwf, float* __restrict__ gpart, int br) {
    int rg = blockIdx.x, hd = blockIdx.y, b = blockIdx.z;
    int d = br + 1;
    int t = threadIdx.x;
    __shared__ ushort cs[48 * 132];   // row stride 132 to break bank aliasing
    float acc[3] = {0.f, 0.f, 0.f};
    for (int yi = 0; yi < 8; ++yi) {
        int y = rg * 8 + yi;
        __syncthreads();  // previous iteration's readers done before overwrite
        for (int e = t; e < 48 * 128; e += 256) {
            int cl = e >> 7, xx = e & 127;
            int cg = (cl < 24) ? (hd * 24 + cl) : (192 + hd * 24 + (cl - 24));
            const ushort* base = qkv + ((size_t)(b * 576 + cg)) * HW;
            const float* w = dwf + (br * 576 + cg) * 9;
            float a = 0.f;
#pragma unroll
            for (int ky = 0; ky < 3; ++ky) {
                int yy = y + d * (ky - 1);
                if ((unsigned)yy < 128u) {
#pragma unroll
                    for (int kx = 0; kx < 3; ++kx) {
                        int x2 = xx + d * (kx - 1);
                        if ((unsigned)x2 < 128u)
                            a = fmaf(bf2f(base[yy * 128 + x2]), w[ky * 3 + kx], a);
                    }
                }
            }
            cs[cl * 132 + xx] = f2bf(a);
        }
        __syncthreads();
#pragma unroll
        for (int pi = 0; pi < 3; ++pi) {
            int p = t + pi * 256;
            if (p >= 624) break;
            int i, j;
            if (p < 576)      { i = p / 24;         j = 24 + p % 24; }
            else if (p < 600) { i = p - 576;        j = i; }
            else              { i = 24 + (p - 600); j = i; }
            const ushort* ra = cs + i * 132;
            const ushort* rb = cs + j * 132;
            float s = acc[pi];
            for (int xi = 0; xi < 128; ++xi)
                s = fmaf(bf2f(ra[xi]), bf2f(rb[xi]), s);
            acc[pi] = s;
        }
    }
    float* gp = gpart + ((size_t)((b * 8 + hd) * 16 + rg)) * 624;
#pragma unroll
    for (int pi = 0; pi < 3; ++pi) {
        int p = t + pi * 256;
        if (p < 624) gp[p] = acc[pi];
    }
}

// ---- reduce gram partials, softmax, fold with w_proj: Pt[b][c][o] ----
__global__ __launch_bounds__(256) void attn_p(const float* __restrict__ gpart,
    const float* __restrict__ wprojf, const float* __restrict__ tempf,
    float* __restrict__ Pt, int br) {
    int otile = blockIdx.x; int b = blockIdx.y;
    int t = threadIdx.x;
    __shared__ float G[8][624];
    __shared__ float A[8][24][24];
    for (int e = t; e < 8 * 624; e += 256) {
        int hd = e / 624, idx = e % 624;
        const float* gp = gpart + ((size_t)((b * 8 + hd) * 16)) * 624 + idx;
        float s = 0.f;
#pragma unroll
        for (int rgi = 0; rgi < 16; ++rgi) s += gp[(size_t)rgi * 624];
        G[hd][idx] = s;
    }
    __syncthreads();
    if (t < 192) {
        int hd = t / 24, i = t % 24;
        const float* g = G[hd];
        float dq = fmaxf(sqrtf(fmaxf(g[576 + i], 0.f)), 1e-12f);
        float tv = tempf[hd];
        float lg[24]; float mx = -1e30f;
#pragma unroll
        for (int j = 0; j < 24; ++j) {
            float kn = fmaxf(sqrtf(fmaxf(g[600 + j], 0.f)), 1e-12f);
            lg[j] = g[i * 24 + j] / (dq * kn) * tv;
            mx = fmaxf(mx, lg[j]);
        }
        float sum = 0.f;
#pragma unroll
        for (int j = 0; j < 24; ++j) { lg[j] = __expf(lg[j] - mx); sum += lg[j]; }
        float inv = 1.f / sum;
#pragma unroll
        for (int j = 0; j < 24; ++j) A[hd][i][j] = lg[j] * inv;
    }
    __syncthreads();
    for (int e = t; e < 24 * 192; e += 256) {
        int o = otile * 24 + (e % 24);
        int c = e / 24;
        int hd = c / 24, dd = c % 24;
        const float* wr = wprojf + o * 576 + br * 192 + hd * 24;
        float s = 0.f;
#pragma unroll
        for (int i = 0; i < 24; ++i) s = fmaf(wr[i], A[hd][i][dd], s);
        Pt[(size_t)b * 36864 + c * 192 + o] = s;
    }
}

// ---- fused dwconv(v) + y += Pt @ conv_v ; block = (image row, batch) ----
__global__ __launch_bounds__(256) void proj_fused(const ushort* __restrict__ qkv,
    const float* __restrict__ dwf, const float* __restrict__ Pt,
    const int* __restrict__ flag, void* __restrict__ outv, int br) {
    int fl = *flag;
    int y = blockIdx.x, b = blockIdx.y;
    int d = br + 1;
    int t = threadIdx.x; int n = t & 127; int half = t >> 7;
    int n0 = y << 7;
    __shared__ ushort vs[192 * 128];
    for (int e = t; e < 192 * 128; e += 256) {
        int c = e >> 7, xx = e & 127;
        const ushort* base = qkv + ((size_t)(b * 576 + 384 + c)) * HW;
        const float* w = dwf + (br * 576 + 384 + c) * 9;
        float a = 0.f;
#pragma unroll
        for (int ky = 0; ky < 3; ++ky) {
            int yy = y + d * (ky - 1);
            if ((unsigned)yy < 128u) {
#pragma unroll
                for (int kx = 0; kx < 3; ++kx) {
                    int x2 = xx + d * (kx - 1);
                    if ((unsigned)x2 < 128u)
                        a = fmaf(bf2f(base[yy * 128 + x2]), w[ky * 3 + kx], a);
                }
            }
        }
        vs[e] = f2bf(a);
    }
    __syncthreads();
    const float* P = Pt + (size_t)b * 36864;
    for (int oc = 0; oc < 3; ++oc) {
        int o0 = oc * 64 + half * 32;
        float acc[32];
#pragma unroll
        for (int j = 0; j < 32; ++j) acc[j] = 0.f;
        for (int c = 0; c < 192; ++c) {
            float xv = bf2f(vs[(c << 7) + n]);
            const float* pr = P + c * 192 + o0;  // wave-uniform row
#pragma unroll
            for (int j = 0; j < 32; ++j) acc[j] = fmaf(pr[j], xv, acc[j]);
        }
        size_t obase = ((size_t)(b * 192 + o0)) * HW + n0 + n;
        if (fl) {
            float* dst = (float*)outv + obase;
            if (br == 0) {
#pragma unroll
                for (int j = 0; j < 32; ++j) dst[(size_t)j * HW] = acc[j];
            } else {
#pragma unroll
                for (int j = 0; j < 32; ++j) dst[(size_t)j * HW] += acc[j];
            }
        } else {
            ushort* dst = (ushort*)outv + obase;
            if (br == 0) {
#pragma unroll
                for (int j = 0; j < 32; ++j) dst[(size_t)j * HW] = f2bf(acc[j]);
            } else {
#pragma unroll
                for (int j = 0; j < 32; ++j) {
                    size_t off = (size_t)j * HW;
                    dst[off] = f2bf(bf2f(dst[off]) + acc[j]);
                }
            }
        }
    }
}

extern "C" void kernel_launch(void* const* d_in, const int* in_sizes, int n_in,
                              void* d_out, int out_size, void* d_ws, size_t ws_size,
                              hipStream_t stream) {
    const void* x    = d_in[0];
    const void* wqkv = d_in[1];
    const void* dw0  = d_in[2];
    const void* dw1  = d_in[3];
    const void* dw2  = d_in[4];
    const void* wpr  = d_in[5];
    const void* temp = d_in[6];

    char* ws = (char*)d_ws;
    ushort* qkv   = (ushort*)(ws);                    // 150,994,944 B
    float* gpart  = (float*)(ws + 150994944);         //   2,555,904 B
    float* Pt     = (float*)(ws + 153550848);         //   1,179,648 B
    float* wqkv_t = (float*)(ws + 154730496);         //     442,368 B
    float* wprojf = (float*)(ws + 155172864);         //     442,368 B
    float* dwf    = (float*)(ws + 155615232);         //      62,208 B
    float* tempf  = (float*)(ws + 155677440);         //          32 B
    int*   flag   = (int*)(ws + 155677472);           //           4 B (~155.7 MB)

    detect_dtype<<<1, 256, 0, stream>>>((const ushort*)x, flag);
    convert_weights<<<925, 256, 0, stream>>>(wqkv, dw0, dw1, dw2, wpr, temp, flag,
                                             wqkv_t, dwf, wprojf, tempf);
    qkv_gemm<<<1024, 256, 0, stream>>>(x, wqkv_t, flag, qkv);
    for (int br = 0; br < 3; ++br) {
        gram_fused<<<dim3(16, 8, 8), 256, 0, stream>>>(qkv, dwf, gpart, br);
        attn_p<<<dim3(8, 8), 256, 0, stream>>>(gpart, wprojf, tempf, Pt, br);
        proj_fused<<<dim3(128, 8), 256, 0, stream>>>(qkv, dwf, Pt, flag, d_out, br);
    }
}

// Round 4
// 2480.529 us; speedup vs baseline: 2.1524x; 2.1524x over previous
//
#include <hip/hip_runtime.h>

#define HW 16384
typedef unsigned int uint32;
typedef unsigned short ushort;
typedef __attribute__((ext_vector_type(8))) short short8;
typedef __attribute__((ext_vector_type(4))) float floatx4;

__device__ __forceinline__ float bf2f(ushort u) {
    union { uint32 i; float f; } x; x.i = ((uint32)u) << 16; return x.f;
}
__device__ __forceinline__ ushort f2bf(float f) {
    union { float f; uint32 i; } x; x.f = f;
    uint32 r = x.i + 0x7fffu + ((x.i >> 16) & 1u);
    return (ushort)(r >> 16);
}

// ---- dtype detector: fp32 data read as bf16 halves has wild exponents ----
__global__ __launch_bounds__(256) void detect_dtype(const ushort* __restrict__ x,
                                                    int* __restrict__ flag) {
    __shared__ int cnt;
    if (threadIdx.x == 0) cnt = 0;
    __syncthreads();
    int c = 0;
    for (int i = threadIdx.x; i < 8192; i += 256) {
        int e = (x[i] >> 7) & 0xFF;
        if (e >= 200) c++;
    }
    atomicAdd(&cnt, c);
    __syncthreads();
    if (threadIdx.x == 0) *flag = (cnt > 100) ? 1 : 0;  // 1 => inputs are fp32
}

// ---- weight convert: wqkv -> bf16 [576][192]; dw,wproj,temp -> fp32 ----
__global__ __launch_bounds__(256) void convert_weights(
    const void* __restrict__ wqkv, const void* __restrict__ dw0,
    const void* __restrict__ dw1, const void* __restrict__ dw2,
    const void* __restrict__ wproj, const void* __restrict__ temp,
    const int* __restrict__ flag,
    ushort* __restrict__ wbf, float* __restrict__ dwf,
    float* __restrict__ wprojf, float* __restrict__ tempf) {
    int fl = *flag;
    int idx = blockIdx.x * 256 + threadIdx.x;
#define RD(p, k) (fl ? ((const float*)(p))[k] : bf2f(((const ushort*)(p))[k]))
    if (idx < 110592) {           // w_qkv [576][192] row-major bf16 (k-contiguous)
        wbf[idx] = f2bf(RD(wqkv, idx));
        return;
    }
    idx -= 110592;
    if (idx < 15552) {            // 3 x [576*9]
        const void* p = (idx < 5184) ? dw0 : ((idx < 10368) ? dw1 : dw2);
        dwf[idx] = RD(p, idx % 5184);
        return;
    }
    idx -= 15552;
    if (idx < 110592) {           // w_proj [192][576] row-major fp32
        wprojf[idx] = RD(wproj, idx);
        return;
    }
    idx -= 110592;
    if (idx < 8) tempf[idx] = RD(temp, idx);
#undef RD
}

// ---- qkv = W @ x via MFMA 16x16x32 bf16. Block: 128 n, all 576 o. ----
// B staged fragment-major in LDS: fb[(s*8+nt)*264 + (q*16+r)*4 + j2] (uint32),
// so each b-frag is one lane-linear ds_read_b128. A frags read from global wbf.
__global__ __launch_bounds__(256, 3) void qkv_mfma(const void* __restrict__ xv,
    const ushort* __restrict__ wbf, const int* __restrict__ flag,
    ushort* __restrict__ qkv) {
    int fl = *flag;
    int blk = blockIdx.x;
    int b = blk >> 7; int n0 = (blk & 127) << 7;
    int t = threadIdx.x;
    __shared__ uint32 fb[12672];  // 6 k-steps * 8 n-subtiles * 264 (256 + 8 pad)
    size_t xbase = (size_t)b * 192 * HW + n0;
    for (int e = t; e < 12288; e += 256) {
        int n = e & 127, c2 = e >> 7;
        int c = c2 * 2;
        float v0, v1;
        if (fl) {
            const float* xp = (const float*)xv + xbase;
            v0 = xp[(size_t)c * HW + n]; v1 = xp[(size_t)(c + 1) * HW + n];
        } else {
            const ushort* xp = (const ushort*)xv + xbase;
            v0 = bf2f(xp[(size_t)c * HW + n]); v1 = bf2f(xp[(size_t)(c + 1) * HW + n]);
        }
        uint32 pk = (uint32)f2bf(v0) | ((uint32)f2bf(v1) << 16);
        int s = c >> 5, q = (c >> 3) & 3, j2 = c2 & 3;
        int nt = n >> 4, r = n & 15;
        fb[(s * 8 + nt) * 264 + (q * 16 + r) * 4 + j2] = pk;
    }
    __syncthreads();
    int w = t >> 6, lane = t & 63, q = lane >> 4, rr = lane & 15;
    for (int oc = 0; oc < 9; ++oc) {
        int o0 = oc * 64 + w * 16;
        const ushort* arow = wbf + (size_t)(o0 + rr) * 192;
        floatx4 acc[8];
#pragma unroll
        for (int nt = 0; nt < 8; ++nt) acc[nt] = (floatx4){0.f, 0.f, 0.f, 0.f};
        for (int s = 0; s < 6; ++s) {
            short8 af = *(const short8*)(arow + 32 * s + 8 * q);
            const uint32* bb = fb + s * 8 * 264 + (q * 16 + rr) * 4;
#pragma unroll
            for (int nt = 0; nt < 8; ++nt) {
                short8 bfr = *(const short8*)(bb + nt * 264);
                acc[nt] = __builtin_amdgcn_mfma_f32_16x16x32_bf16(af, bfr, acc[nt], 0, 0, 0);
            }
        }
        // C layout: row(=o) = q*4+reg, col(=n) = rr  [m89/m91 verified]
        ushort* drow = qkv + ((size_t)(b * 576 + o0 + q * 4)) * HW + n0 + rr;
#pragma unroll
        for (int nt = 0; nt < 8; ++nt)
#pragma unroll
            for (int reg = 0; reg < 4; ++reg)
                drow[(size_t)reg * HW + nt * 16] = f2bf(acc[nt][reg]);
    }
}

// ---- fused dwconv(q,k) + gram partials; block = (rowgroup, head, batch) ----
__global__ __launch_bounds__(256) void gram_fused(const ushort* __restrict__ qkv,
    const float* __restrict__ dwf, float* __restrict__ gpart, int br) {
    int rg = blockIdx.x, hd = blockIdx.y, b = blockIdx.z;
    int d = br + 1;
    int t = threadIdx.x;
    __shared__ ushort cs[48 * 132];   // row stride 132 to break bank aliasing
    float acc[3] = {0.f, 0.f, 0.f};
    for (int yi = 0; yi < 8; ++yi) {
        int y = rg * 8 + yi;
        __syncthreads();
        for (int e = t; e < 48 * 128; e += 256) {
            int cl = e >> 7, xx = e & 127;
            int cg = (cl < 24) ? (hd * 24 + cl) : (192 + hd * 24 + (cl - 24));
            const ushort* base = qkv + ((size_t)(b * 576 + cg)) * HW;
            const float* w = dwf + (br * 576 + cg) * 9;
            float a = 0.f;
#pragma unroll
            for (int ky = 0; ky < 3; ++ky) {
                int yy = y + d * (ky - 1);
                if ((unsigned)yy < 128u) {
#pragma unroll
                    for (int kx = 0; kx < 3; ++kx) {
                        int x2 = xx + d * (kx - 1);
                        if ((unsigned)x2 < 128u)
                            a = fmaf(bf2f(base[yy * 128 + x2]), w[ky * 3 + kx], a);
                    }
                }
            }
            cs[cl * 132 + xx] = f2bf(a);
        }
        __syncthreads();
        const uint32* cs32 = (const uint32*)cs;
#pragma unroll
        for (int pi = 0; pi < 3; ++pi) {
            int p = t + pi * 256;
            if (p >= 624) break;
            int i, j;
            if (p < 576)      { i = p / 24;         j = 24 + p % 24; }
            else if (p < 600) { i = p - 576;        j = i; }
            else              { i = 24 + (p - 600); j = i; }
            const uint32* ra = cs32 + i * 66;
            const uint32* rb = cs32 + j * 66;
            float s = acc[pi];
            for (int xi = 0; xi < 64; ++xi) {
                uint32 ua = ra[xi], ub = rb[xi];
                s = fmaf(bf2f((ushort)(ua & 0xffff)), bf2f((ushort)(ub & 0xffff)), s);
                s = fmaf(bf2f((ushort)(ua >> 16)), bf2f((ushort)(ub >> 16)), s);
            }
            acc[pi] = s;
        }
    }
    float* gp = gpart + ((size_t)((b * 8 + hd) * 16 + rg)) * 624;
#pragma unroll
    for (int pi = 0; pi < 3; ++pi) {
        int p = t + pi * 256;
        if (p < 624) gp[p] = acc[pi];
    }
}

// ---- reduce gram, softmax, fold with w_proj -> Pbf[br][o][c] bf16 ----
__global__ __launch_bounds__(256) void attn_p(const float* __restrict__ gpart,
    const float* __restrict__ wprojf, const float* __restrict__ tempf,
    ushort* __restrict__ Pbf, int br) {
    int otile = blockIdx.x; int b_ = blockIdx.y;
    int t = threadIdx.x;
    __shared__ float G[8][624];
    __shared__ float A[8][24][24];
    for (int e = t; e < 8 * 624; e += 256) {
        int hd = e / 624, idx = e % 624;
        const float* gp = gpart + ((size_t)((b_ * 8 + hd) * 16)) * 624 + idx;
        float s = 0.f;
#pragma unroll
        for (int rgi = 0; rgi < 16; ++rgi) s += gp[(size_t)rgi * 624];
        G[hd][idx] = s;
    }
    __syncthreads();
    if (t < 192) {
        int hd = t / 24, i = t % 24;
        const float* g = G[hd];
        float dq = fmaxf(sqrtf(fmaxf(g[576 + i], 0.f)), 1e-12f);
        float tv = tempf[hd];
        float lg[24]; float mx = -1e30f;
#pragma unroll
        for (int j = 0; j < 24; ++j) {
            float kn = fmaxf(sqrtf(fmaxf(g[600 + j], 0.f)), 1e-12f);
            lg[j] = g[i * 24 + j] / (dq * kn) * tv;
            mx = fmaxf(mx, lg[j]);
        }
        float sum = 0.f;
#pragma unroll
        for (int j = 0; j < 24; ++j) { lg[j] = __expf(lg[j] - mx); sum += lg[j]; }
        float inv = 1.f / sum;
#pragma unroll
        for (int j = 0; j < 24; ++j) A[hd][i][j] = lg[j] * inv;
    }
    __syncthreads();
    // Pbf[b][br][o][c], c = hd*24+dd: P[o][c] = sum_i wproj[o][br*192+hd*24+i]*A[hd][i][dd]
    for (int e = t; e < 24 * 192; e += 256) {
        int o = otile * 24 + (e % 24);
        int c = e / 24;
        int hd = c / 24, dd = c % 24;
        const float* wr = wprojf + o * 576 + br * 192 + hd * 24;
        float s = 0.f;
#pragma unroll
        for (int i = 0; i < 24; ++i) s = fmaf(wr[i], A[hd][i][dd], s);
        Pbf[((size_t)(b_ * 3 + br) * 192 + o) * 192 + c] = f2bf(s);
    }
}

// ---- fused conv(v) + MFMA proj for ALL branches; block = (row y, batch) ----
__global__ __launch_bounds__(256, 2) void proj_mfma(const ushort* __restrict__ qkv,
    const float* __restrict__ dwf, const ushort* __restrict__ Pbf,
    const int* __restrict__ flag, void* __restrict__ outv) {
    int fl = *flag;
    int y = blockIdx.x, b = blockIdx.y;
    int t = threadIdx.x;
    __shared__ uint32 fb[12672];
    int w = t >> 6, lane = t & 63, q = lane >> 4, rr = lane & 15;
    floatx4 acc[3][8];
#pragma unroll
    for (int ot = 0; ot < 3; ++ot)
#pragma unroll
        for (int nt = 0; nt < 8; ++nt) acc[ot][nt] = (floatx4){0.f, 0.f, 0.f, 0.f};
    for (int br = 0; br < 3; ++br) {
        int d = br + 1;
        __syncthreads();
        ushort* fbs = (ushort*)fb;
        for (int e = t; e < 24576; e += 256) {
            int xx = e & 127, c = e >> 7;
            const ushort* base = qkv + ((size_t)(b * 576 + 384 + c)) * HW;
            const float* wv = dwf + (br * 576 + 384 + c) * 9;
            float a = 0.f;
#pragma unroll
            for (int ky = 0; ky < 3; ++ky) {
                int yy = y + d * (ky - 1);
                if ((unsigned)yy < 128u) {
#pragma unroll
                    for (int kx = 0; kx < 3; ++kx) {
                        int x2 = xx + d * (kx - 1);
                        if ((unsigned)x2 < 128u)
                            a = fmaf(bf2f(base[yy * 128 + x2]), wv[ky * 3 + kx], a);
                    }
                }
            }
            int s = c >> 5, qq = (c >> 3) & 3, j = c & 7;
            int nt = xx >> 4, r = xx & 15;
            fbs[((s * 8 + nt) * 264 + (qq * 16 + r) * 4) * 2 + j] = f2bf(a);
        }
        __syncthreads();
        for (int s = 0; s < 6; ++s) {
            short8 bfr[8];
            const uint32* bb = fb + s * 8 * 264 + (q * 16 + rr) * 4;
#pragma unroll
            for (int nt = 0; nt < 8; ++nt) bfr[nt] = *(const short8*)(bb + nt * 264);
#pragma unroll
            for (int ot = 0; ot < 3; ++ot) {
                int o0 = (w * 3 + ot) * 16;
                short8 af = *(const short8*)(Pbf + ((size_t)(b * 3 + br) * 192 + o0 + rr) * 192
                                             + 32 * s + 8 * q);
#pragma unroll
                for (int nt = 0; nt < 8; ++nt)
                    acc[ot][nt] = __builtin_amdgcn_mfma_f32_16x16x32_bf16(af, bfr[nt], acc[ot][nt], 0, 0, 0);
            }
        }
    }
    // epilogue: o = (w*3+ot)*16 + q*4 + reg, n = y*128 + nt*16 + rr
#pragma unroll
    for (int ot = 0; ot < 3; ++ot) {
        int o0 = (w * 3 + ot) * 16 + q * 4;
        size_t obase = ((size_t)(b * 192 + o0)) * HW + y * 128 + rr;
        if (fl) {
            float* dst = (float*)outv + obase;
#pragma unroll
            for (int nt = 0; nt < 8; ++nt)
#pragma unroll
                for (int reg = 0; reg < 4; ++reg)
                    dst[(size_t)reg * HW + nt * 16] = acc[ot][nt][reg];
        } else {
            ushort* dst = (ushort*)outv + obase;
#pragma unroll
            for (int nt = 0; nt < 8; ++nt)
#pragma unroll
                for (int reg = 0; reg < 4; ++reg)
                    dst[(size_t)reg * HW + nt * 16] = f2bf(acc[ot][nt][reg]);
        }
    }
}

extern "C" void kernel_launch(void* const* d_in, const int* in_sizes, int n_in,
                              void* d_out, int out_size, void* d_ws, size_t ws_size,
                              hipStream_t stream) {
    const void* x    = d_in[0];
    const void* wqkv = d_in[1];
    const void* dw0  = d_in[2];
    const void* dw1  = d_in[3];
    const void* dw2  = d_in[4];
    const void* wpr  = d_in[5];
    const void* temp = d_in[6];

    char* ws = (char*)d_ws;
    ushort* qkv   = (ushort*)(ws);                    // 150,994,944 B
    float* gpart  = (float*)(ws + 150994944);         //   2,555,904 B
    ushort* Pbf   = (ushort*)(ws + 153550848);        //     221,184 B [8b][3br][192][192]... (b*3+br)
    ushort* wbf   = (ushort*)(ws + 153772032);        //     221,184 B
    float* wprojf = (float*)(ws + 153993216);         //     442,368 B
    float* dwf    = (float*)(ws + 154435584);         //      62,208 B
    float* tempf  = (float*)(ws + 154497792);         //          32 B
    int*   flag   = (int*)(ws + 154497824);           //           4 B

    // NOTE: Pbf is indexed (b*3+br) -> needs 8*3*192*192*2 = 1,769,472 B; placed last to fit
    Pbf = (ushort*)(ws + 154497828 + 4);  // re-point: see layout note
    // Re-layout cleanly:
    //   [0, 150994944)           qkv
    //   [150994944, 153550848)   gpart
    //   [153550848, 153772032)   wbf
    //   [153772032, 154214400)   wprojf
    //   [154214400, 154276608)   dwf
    //   [154276608, 154276640)   tempf
    //   [154276640, 154276644)   flag
    //   [154276648, 156046120)   Pbf (1,769,472 B)
    wbf    = (ushort*)(ws + 153550848);
    wprojf = (float*)(ws + 153772032);
    dwf    = (float*)(ws + 154214400);
    tempf  = (float*)(ws + 154276608);
    flag   = (int*)(ws + 154276640);
    Pbf    = (ushort*)(ws + 154276648);

    detect_dtype<<<1, 256, 0, stream>>>((const ushort*)x, flag);
    convert_weights<<<925, 256, 0, stream>>>(wqkv, dw0, dw1, dw2, wpr, temp, flag,
                                             wbf, dwf, wprojf, tempf);
    qkv_mfma<<<1024, 256, 0, stream>>>(x, wbf, flag, qkv);
    for (int br = 0; br < 3; ++br) {
        gram_fused<<<dim3(16, 8, 8), 256, 0, stream>>>(qkv, dwf, gpart, br);
        attn_p<<<dim3(8, 8), 256, 0, stream>>>(gpart, wprojf, tempf, Pbf, br);
    }
    proj_mfma<<<dim3(128, 8), 256, 0, stream>>>(qkv, dwf, Pbf, flag, d_out);
}